// Round 9
// baseline (254.131 us; speedup 1.0000x reference)
//
#include <hip/hip_runtime.h>

#define NB 4096
#define MM 64
#define DD 256
#define LN_EPS 1e-5f
#define NEG_BIG -1e30f

typedef float f4v __attribute__((ext_vector_type(4)));

// ws layout (floats):
//   [0,       512*DD)         wcat : [wt^T ; wh^T]
//   [WS_HW,   +NB*DD)         hW
//   [WS_CTX,  +2*NB*DD)       ctx  (row = side*NB + b)
#define WS_WCAT 0
#define WS_HW   (512 * DD)
#define WS_CTX  (WS_HW + NB * DD)

// ---------------- prep: blocks 0..31 transpose wt/wh, 32..287 bilinear ----------------
__global__ __launch_bounds__(256)
void k_prep(const float* __restrict__ head_left,
            const float* __restrict__ head_right,
            const float* __restrict__ bw,
            const float* __restrict__ wt,
            const float* __restrict__ wh,
            float* __restrict__ wcat,
            float* __restrict__ hW)
{
    __shared__ float smem[64 * 65];
    const int t = threadIdx.x;

    if (blockIdx.x < 32) {
        const int mat   = blockIdx.x >> 4;
        const int tile  = blockIdx.x & 15;
        const int dBase = (tile >> 2) * 64;
        const int kBase = (tile & 3) * 64;
        const float* __restrict__ w = mat ? wh : wt;
        float (*tile_s)[65] = (float(*)[65])smem;
        const int c  = t & 63;
        const int rr = t >> 6;
        #pragma unroll
        for (int r = rr; r < 64; r += 4)
            tile_s[r][c] = w[(dBase + r) * DD + kBase + c];
        __syncthreads();
        #pragma unroll
        for (int kr = rr; kr < 64; kr += 4)
            wcat[(mat * 256 + kBase + kr) * DD + dBase + c] = tile_s[c][kr];
    } else {
        const int blk  = blockIdx.x - 32;     // 256 blocks x 16 rows
        const int lane = t & 63;
        const int w    = t >> 6;
        float (*weak_s)[DD] = (float(*)[DD])smem;
        #pragma unroll
        for (int r = 0; r < 16; ++r) {
            const size_t idx = (size_t)(blk * 16 + r) * DD + t;
            weak_s[r][t] = head_right[idx] - head_left[idx];
        }
        __syncthreads();

        float4 acc[4];
        #pragma unroll
        for (int r = 0; r < 4; ++r) acc[r] = make_float4(0.f, 0.f, 0.f, 0.f);
        for (int k = 0; k < DD; ++k) {
            const float4 w4 = *(const float4*)(bw + k * DD + 4 * lane);
            #pragma unroll
            for (int r = 0; r < 4; ++r) {
                const float x = weak_s[4 * w + r][k];
                acc[r].x += x * w4.x; acc[r].y += x * w4.y;
                acc[r].z += x * w4.z; acc[r].w += x * w4.w;
            }
        }
        #pragma unroll
        for (int r = 0; r < 4; ++r)
            *(float4*)(hW + (size_t)(blk * 16 + 4 * w + r) * DD + 4 * lane) = acc[r];
    }
}

// ---------------- attn (FROZEN, round-8): shfl-free streams + nontemporal loads ----------------
__global__ __launch_bounds__(256)
void k_attn(const float* __restrict__ rel_left,
            const float* __restrict__ tail_left,
            const float* __restrict__ rel_right,
            const float* __restrict__ tail_right,
            const unsigned char* __restrict__ mask_left,
            const unsigned char* __restrict__ mask_right,
            const float* __restrict__ hW,
            float* __restrict__ ctx)
{
    const int b    = blockIdx.x >> 1;
    const int side = blockIdx.x & 1;
    const int t    = threadIdx.x;
    const int lane = t & 63;
    const int w    = t >> 6;

    const float* __restrict__ rel  = side ? rel_right  : rel_left;
    const float* __restrict__ tail = side ? tail_right : tail_left;
    const unsigned char* __restrict__ mask = side ? mask_right : mask_left;

    __shared__ float part_s[MM][65];
    __shared__ float red_s[MM][5];
    __shared__ float att_s[MM];
    __shared__ float cpart_s[4][DD];

    const float4 hw4 = *(const float4*)(hW + (size_t)b * DD + 4 * lane);
    const float* rp = rel  + (size_t)b * MM * DD + 4 * lane;
    const float* tp = tail + (size_t)b * MM * DD + 4 * lane;

    #pragma unroll
    for (int i = 0; i < 16; ++i) {
        const int m = w * 16 + i;
        const f4v r4 = __builtin_nontemporal_load((const f4v*)(rp + (size_t)m * DD));
        part_s[m][lane] = hw4.x * r4.x + hw4.y * r4.y + hw4.z * r4.z + hw4.w * r4.w;
    }
    __syncthreads();

    {
        const int m = t & 63;
        const int c = t >> 6;
        float s = 0.f;
        #pragma unroll
        for (int j = 0; j < 16; ++j) s += part_s[m][c * 16 + j];
        red_s[m][c] = s;
    }
    __syncthreads();

    if (w == 0) {
        const unsigned char v0 = mask_left[lane];
        const bool mask_u8 = (__ballot(((lane & 3) != 0) && (v0 != 0)) != 0ULL);

        float s = red_s[lane][0] + red_s[lane][1] + red_s[lane][2] + red_s[lane][3];
        const bool msk = mask_u8
            ? (mask[(size_t)b * MM + lane] != 0)
            : (((const int*)(const void*)mask)[(size_t)b * MM + lane] != 0);
        if (msk) s = NEG_BIG;
        float mx = s;
        #pragma unroll
        for (int off = 32; off >= 1; off >>= 1) mx = fmaxf(mx, __shfl_xor(mx, off, 64));
        const float e = __expf(s - mx);
        float sum = e;
        #pragma unroll
        for (int off = 32; off >= 1; off >>= 1) sum += __shfl_xor(sum, off, 64);
        att_s[lane] = e / sum;
    }
    __syncthreads();

    float4 acc = make_float4(0.f, 0.f, 0.f, 0.f);
    #pragma unroll 4
    for (int i = 0; i < 16; ++i) {
        const int m = w * 16 + i;
        const float a  = att_s[m];
        const f4v v = __builtin_nontemporal_load((const f4v*)(tp + (size_t)m * DD));
        acc.x += a * v.x; acc.y += a * v.y; acc.z += a * v.z; acc.w += a * v.w;
    }
    *(float4*)(&cpart_s[w][4 * lane]) = acc;
    __syncthreads();

    const float sum = cpart_s[0][t] + cpart_s[1][t] + cpart_s[2][t] + cpart_s[3][t];
    ctx[(size_t)(side * NB + b) * DD + t] = sum;
}

// ---------------- E: LDS-free, 8 rows/wave, scalar-uniform x loads ----------------
// 256 blocks x 32 rows; wave w owns rows blk*32 + w*8 .. +7.
// x values are wave-uniform -> readfirstlane'd base => s_load path; no LDS.
__global__ __launch_bounds__(256)
void k_outln(const float* __restrict__ ctx,
             const float* __restrict__ head_left,
             const float* __restrict__ head_right,
             const float* __restrict__ wcat,
             const float* __restrict__ gamma,
             const float* __restrict__ beta,
             float* __restrict__ out)
{
    const int blk  = blockIdx.x;            // 256 blocks
    const int t    = threadIdx.x;           // 256 threads, 4 waves
    const int lane = t & 63;
    const int w    = t >> 6;

    const int rg0  = __builtin_amdgcn_readfirstlane(blk * 32 + w * 8);  // wave-uniform
    const int side = rg0 >> 12;             // all 8 rows same side (32 | 4096)
    const int bb0  = rg0 & (NB - 1);
    const float* __restrict__ head = side ? head_right : head_left;

    float4 acc[8];
    #pragma unroll
    for (int r = 0; r < 8; ++r) acc[r] = make_float4(0.f, 0.f, 0.f, 0.f);

    // ---- k half 1: ctx rows against wcat[0:256) ----
    {
        const float* __restrict__ xr = ctx + (size_t)rg0 * DD;   // uniform base
        #pragma unroll 4
        for (int k = 0; k < 256; ++k) {
            const float4 w4 = *(const float4*)(wcat + (size_t)k * DD + 4 * lane);
            #pragma unroll
            for (int r = 0; r < 8; ++r) {
                const float x = xr[r * DD + k];                  // uniform -> s_load
                acc[r].x += x * w4.x; acc[r].y += x * w4.y;
                acc[r].z += x * w4.z; acc[r].w += x * w4.w;
            }
        }
    }
    // ---- k half 2: head rows against wcat[256:512) ----
    {
        const float* __restrict__ xh = head + (size_t)bb0 * DD;  // uniform base
        #pragma unroll 4
        for (int k = 0; k < 256; ++k) {
            const float4 w4 = *(const float4*)(wcat + (size_t)(256 + k) * DD + 4 * lane);
            #pragma unroll
            for (int r = 0; r < 8; ++r) {
                const float x = xh[r * DD + k];                  // uniform -> s_load
                acc[r].x += x * w4.x; acc[r].y += x * w4.y;
                acc[r].z += x * w4.z; acc[r].w += x * w4.w;
            }
        }
    }

    const float4 g4 = *(const float4*)(gamma + 4 * lane);
    const float4 b4 = *(const float4*)(beta  + 4 * lane);

    #pragma unroll
    for (int r = 0; r < 8; ++r) {
        const int rg = rg0 + r;
        const int bb = rg & (NB - 1);
        const float4 h4 = *(const float4*)(head + (size_t)bb * DD + 4 * lane);
        float4 y;
        y.x = fmaxf(acc[r].x, 0.f) + h4.x;
        y.y = fmaxf(acc[r].y, 0.f) + h4.y;
        y.z = fmaxf(acc[r].z, 0.f) + h4.z;
        y.w = fmaxf(acc[r].w, 0.f) + h4.w;

        float s1 = y.x + y.y + y.z + y.w;
        float s2 = y.x * y.x + y.y * y.y + y.z * y.z + y.w * y.w;
        #pragma unroll
        for (int off = 32; off >= 1; off >>= 1) {
            s1 += __shfl_xor(s1, off, 64);
            s2 += __shfl_xor(s2, off, 64);
        }
        const float mu   = s1 * (1.0f / DD);
        const float var  = s2 * (1.0f / DD) - mu * mu;
        const float rstd = rsqrtf(var + LN_EPS);

        f4v o;
        o.x = (y.x - mu) * rstd * g4.x + b4.x;
        o.y = (y.y - mu) * rstd * g4.y + b4.y;
        o.z = (y.z - mu) * rstd * g4.z + b4.z;
        o.w = (y.w - mu) * rstd * g4.w + b4.w;
        __builtin_nontemporal_store(o, (f4v*)(out + (size_t)rg * DD + 4 * lane));
    }
}

extern "C" void kernel_launch(void* const* d_in, const int* in_sizes, int n_in,
                              void* d_out, int out_size, void* d_ws, size_t ws_size,
                              hipStream_t stream) {
    const float* head_left  = (const float*)d_in[0];
    const float* rel_left   = (const float*)d_in[1];
    const float* tail_left  = (const float*)d_in[2];
    const float* head_right = (const float*)d_in[3];
    const float* rel_right  = (const float*)d_in[4];
    const float* tail_right = (const float*)d_in[5];
    const unsigned char* mask_left  = (const unsigned char*)d_in[6];
    const unsigned char* mask_right = (const unsigned char*)d_in[7];
    const float* bw    = (const float*)d_in[8];
    const float* wt    = (const float*)d_in[9];
    const float* wh    = (const float*)d_in[10];
    const float* gamma = (const float*)d_in[11];
    const float* beta  = (const float*)d_in[12];
    float* out = (float*)d_out;

    float* ws   = (float*)d_ws;
    float* wcat = ws + WS_WCAT;
    float* hW   = ws + WS_HW;
    float* ctxb = ws + WS_CTX;

    k_prep <<<dim3(288),  dim3(256), 0, stream>>>(head_left, head_right, bw, wt, wh, wcat, hW);
    k_attn <<<dim3(8192), dim3(256), 0, stream>>>(rel_left, tail_left, rel_right, tail_right,
                                                  mask_left, mask_right, hW, ctxb);
    k_outln<<<dim3(256),  dim3(256), 0, stream>>>(ctxb, head_left, head_right, wcat,
                                                  gamma, beta, out);
}

// Round 10
// 209.756 us; speedup vs baseline: 1.2116x; 1.2116x over previous
//
#include <hip/hip_runtime.h>
#include <hip/hip_bf16.h>

#define NB 4096
#define MM 64
#define DD 256
#define LN_EPS 1e-5f
#define NEG_BIG -1e30f

typedef float f4v __attribute__((ext_vector_type(4)));
typedef __attribute__((ext_vector_type(8))) short bf16x8;
typedef __attribute__((ext_vector_type(4))) float f32x4;

// ws layout:
//   [0, NB*DD) floats                hW
//   A_bf  = (short*)(ws + NB*DD)     [8192][512] bf16  (cols 0:256 = ctx from attn,
//                                                       cols 256:512 = head_side from prep)
//   Bp    = A_bf + 8192*512          [16][256][32] bf16 packed B fragments:
//                                    Bp[kb][c][kr] = Wcat[kb*32+kr][c],
//                                    Wcat[k][c] = k<256 ? wt[c][k] : wh[c][k-256]
#define WS_HW 0

__device__ inline unsigned short f2bf(float x) {
    __hip_bfloat16 h = __float2bfloat16(x);
    return *reinterpret_cast<unsigned short*>(&h);
}

// ---------------- prep ----------------
// blocks 0..15   : pack Bp (bf16 weights)
// blocks 16..47  : head_bf -> A_bf cols [256:512)
// blocks 48..303 : bilinear hW = (hr-hl) @ bw
__global__ __launch_bounds__(256)
void k_prep(const float* __restrict__ head_left,
            const float* __restrict__ head_right,
            const float* __restrict__ bw,
            const float* __restrict__ wt,
            const float* __restrict__ wh,
            short* __restrict__ A_bf,
            short* __restrict__ Bp,
            float* __restrict__ hW)
{
    __shared__ float smem[16 * DD];
    const int t = threadIdx.x;

    if (blockIdx.x < 16) {
        const int kb = blockIdx.x;                 // 0..15
        const float* __restrict__ src = (kb < 8) ? wt : wh;
        const int kbase = (kb & 7) * 32;
        const int c = t;                            // 0..255
        unsigned int words[16];
        #pragma unroll
        for (int i = 0; i < 16; ++i) {
            const float a = src[c * DD + kbase + 2 * i];
            const float b = src[c * DD + kbase + 2 * i + 1];
            words[i] = (unsigned int)f2bf(a) | ((unsigned int)f2bf(b) << 16);
        }
        uint4* dst = (uint4*)(Bp + ((size_t)kb * 256 + c) * 32);
        #pragma unroll
        for (int i = 0; i < 4; ++i) dst[i] = *(uint4*)&words[4 * i];
    } else if (blockIdx.x < 48) {
        const int hb   = blockIdx.x - 16;          // 0..31, 256 rows each
        const int rg0  = hb * 256;
        const int side = rg0 >> 12;
        const int bb0  = rg0 & (NB - 1);
        const float* __restrict__ head = side ? head_right : head_left;
        for (int r = 0; r < 256; ++r) {
            const float v = head[(size_t)(bb0 + r) * DD + t];
            A_bf[(size_t)(rg0 + r) * 512 + 256 + t] = (short)f2bf(v);
        }
    } else {
        const int blk  = blockIdx.x - 48;          // 256 blocks x 16 rows
        const int lane = t & 63;
        const int w    = t >> 6;
        float (*weak_s)[DD] = (float(*)[DD])smem;
        #pragma unroll
        for (int r = 0; r < 16; ++r) {
            const size_t idx = (size_t)(blk * 16 + r) * DD + t;
            weak_s[r][t] = head_right[idx] - head_left[idx];
        }
        __syncthreads();

        float4 acc[4];
        #pragma unroll
        for (int r = 0; r < 4; ++r) acc[r] = make_float4(0.f, 0.f, 0.f, 0.f);
        for (int k = 0; k < DD; ++k) {
            const float4 w4 = *(const float4*)(bw + k * DD + 4 * lane);
            #pragma unroll
            for (int r = 0; r < 4; ++r) {
                const float x = weak_s[4 * w + r][k];
                acc[r].x += x * w4.x; acc[r].y += x * w4.y;
                acc[r].z += x * w4.z; acc[r].w += x * w4.w;
            }
        }
        #pragma unroll
        for (int r = 0; r < 4; ++r)
            *(float4*)(hW + (size_t)(blk * 16 + 4 * w + r) * DD + 4 * lane) = acc[r];
    }
}

// ---------------- attn (FROZEN round-8) + bf16 ctx emit ----------------
__global__ __launch_bounds__(256)
void k_attn(const float* __restrict__ rel_left,
            const float* __restrict__ tail_left,
            const float* __restrict__ rel_right,
            const float* __restrict__ tail_right,
            const unsigned char* __restrict__ mask_left,
            const unsigned char* __restrict__ mask_right,
            const float* __restrict__ hW,
            short* __restrict__ A_bf)
{
    const int b    = blockIdx.x >> 1;
    const int side = blockIdx.x & 1;
    const int t    = threadIdx.x;
    const int lane = t & 63;
    const int w    = t >> 6;

    const float* __restrict__ rel  = side ? rel_right  : rel_left;
    const float* __restrict__ tail = side ? tail_right : tail_left;
    const unsigned char* __restrict__ mask = side ? mask_right : mask_left;

    __shared__ float part_s[MM][65];
    __shared__ float red_s[MM][5];
    __shared__ float att_s[MM];
    __shared__ float cpart_s[4][DD];

    const float4 hw4 = *(const float4*)(hW + (size_t)b * DD + 4 * lane);
    const float* rp = rel  + (size_t)b * MM * DD + 4 * lane;
    const float* tp = tail + (size_t)b * MM * DD + 4 * lane;

    #pragma unroll
    for (int i = 0; i < 16; ++i) {
        const int m = w * 16 + i;
        const f4v r4 = __builtin_nontemporal_load((const f4v*)(rp + (size_t)m * DD));
        part_s[m][lane] = hw4.x * r4.x + hw4.y * r4.y + hw4.z * r4.z + hw4.w * r4.w;
    }
    __syncthreads();

    {
        const int m = t & 63;
        const int c = t >> 6;
        float s = 0.f;
        #pragma unroll
        for (int j = 0; j < 16; ++j) s += part_s[m][c * 16 + j];
        red_s[m][c] = s;
    }
    __syncthreads();

    if (w == 0) {
        const unsigned char v0 = mask_left[lane];
        const bool mask_u8 = (__ballot(((lane & 3) != 0) && (v0 != 0)) != 0ULL);

        float s = red_s[lane][0] + red_s[lane][1] + red_s[lane][2] + red_s[lane][3];
        const bool msk = mask_u8
            ? (mask[(size_t)b * MM + lane] != 0)
            : (((const int*)(const void*)mask)[(size_t)b * MM + lane] != 0);
        if (msk) s = NEG_BIG;
        float mx = s;
        #pragma unroll
        for (int off = 32; off >= 1; off >>= 1) mx = fmaxf(mx, __shfl_xor(mx, off, 64));
        const float e = __expf(s - mx);
        float sum = e;
        #pragma unroll
        for (int off = 32; off >= 1; off >>= 1) sum += __shfl_xor(sum, off, 64);
        att_s[lane] = e / sum;
    }
    __syncthreads();

    float4 acc = make_float4(0.f, 0.f, 0.f, 0.f);
    #pragma unroll 4
    for (int i = 0; i < 16; ++i) {
        const int m = w * 16 + i;
        const float a  = att_s[m];
        const f4v v = __builtin_nontemporal_load((const f4v*)(tp + (size_t)m * DD));
        acc.x += a * v.x; acc.y += a * v.y; acc.z += a * v.z; acc.w += a * v.w;
    }
    *(float4*)(&cpart_s[w][4 * lane]) = acc;
    __syncthreads();

    const float sum = cpart_s[0][t] + cpart_s[1][t] + cpart_s[2][t] + cpart_s[3][t];
    A_bf[(size_t)(side * NB + b) * 512 + t] = (short)f2bf(sum);
}

// ---------------- fuse: MFMA GEMM [32x256,K=512] + relu + residual + LN ----------------
// 256 blocks x 512 threads (8 waves). wave w: rows wr*16..+15 (wr=w>>2), cols wc*64..+63 (wc=w&3).
// A frag:  lane l -> row (l&15), k = ks*32 + (l>>4)*8 + j   (16B contiguous)
// B frag:  lane l -> col (l&15), same k rule via packed Bp   (16B contiguous)
// C/D:     col = lane&15, row = (lane>>4)*4 + reg            [HW-verified m89]
__global__ __launch_bounds__(512)
void k_fuse(const short* __restrict__ A_bf,
            const short* __restrict__ Bp,
            const float* __restrict__ head_left,
            const float* __restrict__ head_right,
            const float* __restrict__ gamma,
            const float* __restrict__ beta,
            float* __restrict__ out)
{
    const int blk  = blockIdx.x;          // 256 blocks x 32 rows
    const int t    = threadIdx.x;
    const int lane = t & 63;
    const int w    = t >> 6;
    const int wr   = w >> 2;
    const int wc   = w & 3;
    const int rg0  = blk * 32;

    __shared__ float x_s[32][260];        // pad 260: acc-write groups 2-way only (free)

    f32x4 acc[4] = {f32x4{0,0,0,0}, f32x4{0,0,0,0}, f32x4{0,0,0,0}, f32x4{0,0,0,0}};

    const short* ap = A_bf + (size_t)(rg0 + wr * 16 + (lane & 15)) * 512 + (lane >> 4) * 8;
    const short* bp = Bp + (size_t)(wc * 64 + (lane & 15)) * 32 + (lane >> 4) * 8;

    #pragma unroll 4
    for (int ks = 0; ks < 16; ++ks) {
        const bf16x8 a = *(const bf16x8*)(ap + ks * 32);
        #pragma unroll
        for (int ct = 0; ct < 4; ++ct) {
            const bf16x8 b = *(const bf16x8*)(bp + (size_t)ks * 8192 + ct * 512);
            acc[ct] = __builtin_amdgcn_mfma_f32_16x16x32_bf16(a, b, acc[ct], 0, 0, 0);
        }
    }

    #pragma unroll
    for (int ct = 0; ct < 4; ++ct)
        #pragma unroll
        for (int q = 0; q < 4; ++q)
            x_s[wr * 16 + (lane >> 4) * 4 + q][wc * 64 + ct * 16 + (lane & 15)] = acc[ct][q];
    __syncthreads();

    // LN: wave w owns rows 4w..4w+3; lane covers cols 4*lane..+3
    const int  side = rg0 >> 12;
    const float* __restrict__ head = side ? head_right : head_left;
    const float4 g4 = *(const float4*)(gamma + 4 * lane);
    const float4 b4 = *(const float4*)(beta  + 4 * lane);

    #pragma unroll
    for (int rr = 0; rr < 4; ++rr) {
        const int r  = 4 * w + rr;
        const int rg = rg0 + r;
        const int bb = rg & (NB - 1);
        const float4 v  = *(const float4*)(&x_s[r][4 * lane]);
        const float4 h4 = *(const float4*)(head + (size_t)bb * DD + 4 * lane);
        float4 y;
        y.x = fmaxf(v.x, 0.f) + h4.x;
        y.y = fmaxf(v.y, 0.f) + h4.y;
        y.z = fmaxf(v.z, 0.f) + h4.z;
        y.w = fmaxf(v.w, 0.f) + h4.w;

        float s1 = y.x + y.y + y.z + y.w;
        float s2 = y.x * y.x + y.y * y.y + y.z * y.z + y.w * y.w;
        #pragma unroll
        for (int off = 32; off >= 1; off >>= 1) {
            s1 += __shfl_xor(s1, off, 64);
            s2 += __shfl_xor(s2, off, 64);
        }
        const float mu   = s1 * (1.0f / DD);
        const float var  = s2 * (1.0f / DD) - mu * mu;
        const float rstd = rsqrtf(var + LN_EPS);

        f4v o;
        o.x = (y.x - mu) * rstd * g4.x + b4.x;
        o.y = (y.y - mu) * rstd * g4.y + b4.y;
        o.z = (y.z - mu) * rstd * g4.z + b4.z;
        o.w = (y.w - mu) * rstd * g4.w + b4.w;
        __builtin_nontemporal_store(o, (f4v*)(out + (size_t)rg * DD + 4 * lane));
    }
}

extern "C" void kernel_launch(void* const* d_in, const int* in_sizes, int n_in,
                              void* d_out, int out_size, void* d_ws, size_t ws_size,
                              hipStream_t stream) {
    const float* head_left  = (const float*)d_in[0];
    const float* rel_left   = (const float*)d_in[1];
    const float* tail_left  = (const float*)d_in[2];
    const float* head_right = (const float*)d_in[3];
    const float* rel_right  = (const float*)d_in[4];
    const float* tail_right = (const float*)d_in[5];
    const unsigned char* mask_left  = (const unsigned char*)d_in[6];
    const unsigned char* mask_right = (const unsigned char*)d_in[7];
    const float* bw    = (const float*)d_in[8];
    const float* wt    = (const float*)d_in[9];
    const float* wh    = (const float*)d_in[10];
    const float* gamma = (const float*)d_in[11];
    const float* beta  = (const float*)d_in[12];
    float* out = (float*)d_out;

    float* ws   = (float*)d_ws;
    float* hW   = ws + WS_HW;
    short* A_bf = (short*)(ws + NB * DD);
    short* Bp   = A_bf + (size_t)8192 * 512;

    k_prep <<<dim3(304),  dim3(256), 0, stream>>>(head_left, head_right, bw, wt, wh,
                                                  A_bf, Bp, hW);
    k_attn <<<dim3(8192), dim3(256), 0, stream>>>(rel_left, tail_left, rel_right, tail_right,
                                                  mask_left, mask_right, hW, A_bf);
    k_fuse <<<dim3(256),  dim3(512), 0, stream>>>(A_bf, Bp, head_left, head_right,
                                                  gamma, beta, out);
}

// Round 11
// 206.549 us; speedup vs baseline: 1.2304x; 1.0155x over previous
//
#include <hip/hip_runtime.h>
#include <hip/hip_bf16.h>

#define NB 4096
#define MM 64
#define DD 256
#define LN_EPS 1e-5f
#define NEG_BIG -1e30f

typedef float f4v __attribute__((ext_vector_type(4)));
typedef __attribute__((ext_vector_type(8))) short bf16x8;
typedef __attribute__((ext_vector_type(4))) float f32x4;

// ws layout:
//   [0, NB*DD) floats                hW
//   A_bf  = (short*)(ws + NB*DD)     [8192][512] bf16  (cols 0:256 = ctx from attn,
//                                                       cols 256:512 = head_side from prep)
//   Bp    = A_bf + 8192*512          [16][256][32] bf16 packed B fragments:
//                                    Bp[kb][c][kr] = Wcat[kb*32+kr][c],
//                                    Wcat[k][c] = k<256 ? wt[c][k] : wh[c][k-256]
#define WS_HW 0

__device__ inline unsigned short f2bf(float x) {
    __hip_bfloat16 h = __float2bfloat16(x);
    return *reinterpret_cast<unsigned short*>(&h);
}

// ---------------- prep ----------------
// blocks 0..15   : pack Bp (bf16 weights)
// blocks 16..271 : bilinear hW = (hr-hl) @ bw  +  head bf16 pack (reuses the same loads)
__global__ __launch_bounds__(256)
void k_prep(const float* __restrict__ head_left,
            const float* __restrict__ head_right,
            const float* __restrict__ bw,
            const float* __restrict__ wt,
            const float* __restrict__ wh,
            short* __restrict__ A_bf,
            short* __restrict__ Bp,
            float* __restrict__ hW)
{
    __shared__ float smem[16 * DD];
    const int t = threadIdx.x;

    if (blockIdx.x < 16) {
        const int kb = blockIdx.x;                 // 0..15
        const float* __restrict__ src = (kb < 8) ? wt : wh;
        const int kbase = (kb & 7) * 32;
        const int c = t;                            // 0..255
        unsigned int words[16];
        #pragma unroll
        for (int i = 0; i < 16; ++i) {
            const float a = src[c * DD + kbase + 2 * i];
            const float b = src[c * DD + kbase + 2 * i + 1];
            words[i] = (unsigned int)f2bf(a) | ((unsigned int)f2bf(b) << 16);
        }
        uint4* dst = (uint4*)(Bp + ((size_t)kb * 256 + c) * 32);
        #pragma unroll
        for (int i = 0; i < 4; ++i) dst[i] = *(uint4*)&words[4 * i];
    } else {
        const int blk  = blockIdx.x - 16;          // 256 blocks x 16 rows
        const int lane = t & 63;
        const int w    = t >> 6;
        float (*weak_s)[DD] = (float(*)[DD])smem;
        #pragma unroll
        for (int r = 0; r < 16; ++r) {
            const int  b   = blk * 16 + r;
            const size_t idx = (size_t)b * DD + t;
            const float hl = head_left[idx];
            const float hr = head_right[idx];
            weak_s[r][t] = hr - hl;
            // head bf16 pack into A-matrix right half (free: reuses these loads)
            A_bf[(size_t)b * 512 + 256 + t]        = (short)f2bf(hl);
            A_bf[(size_t)(NB + b) * 512 + 256 + t] = (short)f2bf(hr);
        }
        __syncthreads();

        float4 acc[4];
        #pragma unroll
        for (int r = 0; r < 4; ++r) acc[r] = make_float4(0.f, 0.f, 0.f, 0.f);
        for (int k = 0; k < DD; ++k) {
            const float4 w4 = *(const float4*)(bw + k * DD + 4 * lane);
            #pragma unroll
            for (int r = 0; r < 4; ++r) {
                const float x = weak_s[4 * w + r][k];
                acc[r].x += x * w4.x; acc[r].y += x * w4.y;
                acc[r].z += x * w4.z; acc[r].w += x * w4.w;
            }
        }
        #pragma unroll
        for (int r = 0; r < 4; ++r)
            *(float4*)(hW + (size_t)(blk * 16 + 4 * w + r) * DD + 4 * lane) = acc[r];
    }
}

// ---------------- attn (FROZEN round-8) + bf16 ctx emit ----------------
__global__ __launch_bounds__(256)
void k_attn(const float* __restrict__ rel_left,
            const float* __restrict__ tail_left,
            const float* __restrict__ rel_right,
            const float* __restrict__ tail_right,
            const unsigned char* __restrict__ mask_left,
            const unsigned char* __restrict__ mask_right,
            const float* __restrict__ hW,
            short* __restrict__ A_bf)
{
    const int b    = blockIdx.x >> 1;
    const int side = blockIdx.x & 1;
    const int t    = threadIdx.x;
    const int lane = t & 63;
    const int w    = t >> 6;

    const float* __restrict__ rel  = side ? rel_right  : rel_left;
    const float* __restrict__ tail = side ? tail_right : tail_left;
    const unsigned char* __restrict__ mask = side ? mask_right : mask_left;

    __shared__ float part_s[MM][65];
    __shared__ float red_s[MM][5];
    __shared__ float att_s[MM];
    __shared__ float cpart_s[4][DD];

    const float4 hw4 = *(const float4*)(hW + (size_t)b * DD + 4 * lane);
    const float* rp = rel  + (size_t)b * MM * DD + 4 * lane;
    const float* tp = tail + (size_t)b * MM * DD + 4 * lane;

    #pragma unroll
    for (int i = 0; i < 16; ++i) {
        const int m = w * 16 + i;
        const f4v r4 = __builtin_nontemporal_load((const f4v*)(rp + (size_t)m * DD));
        part_s[m][lane] = hw4.x * r4.x + hw4.y * r4.y + hw4.z * r4.z + hw4.w * r4.w;
    }
    __syncthreads();

    {
        const int m = t & 63;
        const int c = t >> 6;
        float s = 0.f;
        #pragma unroll
        for (int j = 0; j < 16; ++j) s += part_s[m][c * 16 + j];
        red_s[m][c] = s;
    }
    __syncthreads();

    if (w == 0) {
        const unsigned char v0 = mask_left[lane];
        const bool mask_u8 = (__ballot(((lane & 3) != 0) && (v0 != 0)) != 0ULL);

        float s = red_s[lane][0] + red_s[lane][1] + red_s[lane][2] + red_s[lane][3];
        const bool msk = mask_u8
            ? (mask[(size_t)b * MM + lane] != 0)
            : (((const int*)(const void*)mask)[(size_t)b * MM + lane] != 0);
        if (msk) s = NEG_BIG;
        float mx = s;
        #pragma unroll
        for (int off = 32; off >= 1; off >>= 1) mx = fmaxf(mx, __shfl_xor(mx, off, 64));
        const float e = __expf(s - mx);
        float sum = e;
        #pragma unroll
        for (int off = 32; off >= 1; off >>= 1) sum += __shfl_xor(sum, off, 64);
        att_s[lane] = e / sum;
    }
    __syncthreads();

    float4 acc = make_float4(0.f, 0.f, 0.f, 0.f);
    #pragma unroll 4
    for (int i = 0; i < 16; ++i) {
        const int m = w * 16 + i;
        const float a  = att_s[m];
        const f4v v = __builtin_nontemporal_load((const f4v*)(tp + (size_t)m * DD));
        acc.x += a * v.x; acc.y += a * v.y; acc.z += a * v.z; acc.w += a * v.w;
    }
    *(float4*)(&cpart_s[w][4 * lane]) = acc;
    __syncthreads();

    const float sum = cpart_s[0][t] + cpart_s[1][t] + cpart_s[2][t] + cpart_s[3][t];
    A_bf[(size_t)(side * NB + b) * 512 + t] = (short)f2bf(sum);
}

// ---------------- fuse: MFMA GEMM [32x256,K=512] + relu + residual + LN ----------------
// 256 blocks x 512 threads (8 waves). wave w: rows wr*16..+15 (wr=w>>2), cols wc*64..+63 (wc=w&3).
// A frag:  lane l -> row (l&15), k = ks*32 + (l>>4)*8 + j   (16B contiguous, nontemporal)
// B frag:  lane l -> col (l&15), same k rule via packed Bp   (16B contiguous, L2-resident)
// C/D:     col = lane&15, row = (lane>>4)*4 + reg            [HW-verified m89]
__global__ __launch_bounds__(512)
void k_fuse(const short* __restrict__ A_bf,
            const short* __restrict__ Bp,
            const float* __restrict__ head_left,
            const float* __restrict__ head_right,
            const float* __restrict__ gamma,
            const float* __restrict__ beta,
            float* __restrict__ out)
{
    const int blk  = blockIdx.x;          // 256 blocks x 32 rows
    const int t    = threadIdx.x;
    const int lane = t & 63;
    const int w    = t >> 6;
    const int wr   = w >> 2;
    const int wc   = w & 3;
    const int rg0  = blk * 32;

    __shared__ float x_s[32][260];        // pad 260: acc-write groups 2-way only (free)

    f32x4 acc[4] = {f32x4{0,0,0,0}, f32x4{0,0,0,0}, f32x4{0,0,0,0}, f32x4{0,0,0,0}};

    const short* ap = A_bf + (size_t)(rg0 + wr * 16 + (lane & 15)) * 512 + (lane >> 4) * 8;
    const short* bp = Bp + (size_t)(wc * 64 + (lane & 15)) * 32 + (lane >> 4) * 8;

    #pragma unroll 4
    for (int ks = 0; ks < 16; ++ks) {
        const bf16x8 a = __builtin_nontemporal_load((const bf16x8*)(ap + ks * 32));
        #pragma unroll
        for (int ct = 0; ct < 4; ++ct) {
            const bf16x8 b = *(const bf16x8*)(bp + (size_t)ks * 8192 + ct * 512);
            acc[ct] = __builtin_amdgcn_mfma_f32_16x16x32_bf16(a, b, acc[ct], 0, 0, 0);
        }
    }

    #pragma unroll
    for (int ct = 0; ct < 4; ++ct)
        #pragma unroll
        for (int q = 0; q < 4; ++q)
            x_s[wr * 16 + (lane >> 4) * 4 + q][wc * 64 + ct * 16 + (lane & 15)] = acc[ct][q];
    __syncthreads();

    // LN: wave w owns rows 4w..4w+3; lane covers cols 4*lane..+3
    const int  side = rg0 >> 12;
    const float* __restrict__ head = side ? head_right : head_left;
    const float4 g4 = *(const float4*)(gamma + 4 * lane);
    const float4 b4 = *(const float4*)(beta  + 4 * lane);

    #pragma unroll
    for (int rr = 0; rr < 4; ++rr) {
        const int r  = 4 * w + rr;
        const int rg = rg0 + r;
        const int bb = rg & (NB - 1);
        const float4 v  = *(const float4*)(&x_s[r][4 * lane]);
        const float4 h4 = *(const float4*)(head + (size_t)bb * DD + 4 * lane);
        float4 y;
        y.x = fmaxf(v.x, 0.f) + h4.x;
        y.y = fmaxf(v.y, 0.f) + h4.y;
        y.z = fmaxf(v.z, 0.f) + h4.z;
        y.w = fmaxf(v.w, 0.f) + h4.w;

        float s1 = y.x + y.y + y.z + y.w;
        float s2 = y.x * y.x + y.y * y.y + y.z * y.z + y.w * y.w;
        #pragma unroll
        for (int off = 32; off >= 1; off >>= 1) {
            s1 += __shfl_xor(s1, off, 64);
            s2 += __shfl_xor(s2, off, 64);
        }
        const float mu   = s1 * (1.0f / DD);
        const float var  = s2 * (1.0f / DD) - mu * mu;
        const float rstd = rsqrtf(var + LN_EPS);

        f4v o;
        o.x = (y.x - mu) * rstd * g4.x + b4.x;
        o.y = (y.y - mu) * rstd * g4.y + b4.y;
        o.z = (y.z - mu) * rstd * g4.z + b4.z;
        o.w = (y.w - mu) * rstd * g4.w + b4.w;
        __builtin_nontemporal_store(o, (f4v*)(out + (size_t)rg * DD + 4 * lane));
    }
}

extern "C" void kernel_launch(void* const* d_in, const int* in_sizes, int n_in,
                              void* d_out, int out_size, void* d_ws, size_t ws_size,
                              hipStream_t stream) {
    const float* head_left  = (const float*)d_in[0];
    const float* rel_left   = (const float*)d_in[1];
    const float* tail_left  = (const float*)d_in[2];
    const float* head_right = (const float*)d_in[3];
    const float* rel_right  = (const float*)d_in[4];
    const float* rel_r     = rel_right;
    const float* tail_right = (const float*)d_in[5];
    const unsigned char* mask_left  = (const unsigned char*)d_in[6];
    const unsigned char* mask_right = (const unsigned char*)d_in[7];
    const float* bw    = (const float*)d_in[8];
    const float* wt    = (const float*)d_in[9];
    const float* wh    = (const float*)d_in[10];
    const float* gamma = (const float*)d_in[11];
    const float* beta  = (const float*)d_in[12];
    float* out = (float*)d_out;

    float* ws   = (float*)d_ws;
    float* hW   = ws + WS_HW;
    short* A_bf = (short*)(ws + NB * DD);
    short* Bp   = A_bf + (size_t)8192 * 512;

    k_prep <<<dim3(272),  dim3(256), 0, stream>>>(head_left, head_right, bw, wt, wh,
                                                  A_bf, Bp, hW);
    k_attn <<<dim3(8192), dim3(256), 0, stream>>>(rel_left, tail_left, rel_r, tail_right,
                                                  mask_left, mask_right, hW, A_bf);
    k_fuse <<<dim3(256),  dim3(512), 0, stream>>>(A_bf, Bp, head_left, head_right,
                                                  gamma, beta, out);
}

// Round 12
// 206.525 us; speedup vs baseline: 1.2305x; 1.0001x over previous
//
#include <hip/hip_runtime.h>
#include <hip/hip_bf16.h>

#define NB 4096
#define MM 64
#define DD 256
#define LN_EPS 1e-5f
#define NEG_BIG -1e30f

typedef float f4v __attribute__((ext_vector_type(4)));
typedef __attribute__((ext_vector_type(8))) short bf16x8;
typedef __attribute__((ext_vector_type(4))) float f32x4;

// ws layout:
//   [0, NB*DD) floats                hW
//   A_bf  = (short*)(ws + NB*DD)     [8192][256] bf16 ctx (row = side*NB + b)
//   Bp    = A_bf + 8192*256          [16][256][32] bf16 packed B fragments:
//                                    Bp[kb][c][kr] = Wcat[kb*32+kr][c],
//                                    Wcat[k][c] = k<256 ? wt[c][k] : wh[c][k-256]
#define WS_HW 0

__device__ inline unsigned short f2bf(float x) {
    __hip_bfloat16 h = __float2bfloat16(x);
    return *reinterpret_cast<unsigned short*>(&h);
}

// ---------------- prep ----------------
// blocks 0..15   : pack Bp (bf16 weights)
// blocks 16..271 : bilinear hW = (hr-hl) @ bw
__global__ __launch_bounds__(256)
void k_prep(const float* __restrict__ head_left,
            const float* __restrict__ head_right,
            const float* __restrict__ bw,
            const float* __restrict__ wt,
            const float* __restrict__ wh,
            short* __restrict__ Bp,
            float* __restrict__ hW)
{
    __shared__ float smem[16 * DD];
    const int t = threadIdx.x;

    if (blockIdx.x < 16) {
        const int kb = blockIdx.x;                 // 0..15
        const float* __restrict__ src = (kb < 8) ? wt : wh;
        const int kbase = (kb & 7) * 32;
        const int c = t;                            // 0..255
        unsigned int words[16];
        #pragma unroll
        for (int i = 0; i < 16; ++i) {
            const float a = src[c * DD + kbase + 2 * i];
            const float b = src[c * DD + kbase + 2 * i + 1];
            words[i] = (unsigned int)f2bf(a) | ((unsigned int)f2bf(b) << 16);
        }
        uint4* dst = (uint4*)(Bp + ((size_t)kb * 256 + c) * 32);
        #pragma unroll
        for (int i = 0; i < 4; ++i) dst[i] = *(uint4*)&words[4 * i];
    } else {
        const int blk  = blockIdx.x - 16;          // 256 blocks x 16 rows
        const int lane = t & 63;
        const int w    = t >> 6;
        float (*weak_s)[DD] = (float(*)[DD])smem;
        #pragma unroll
        for (int r = 0; r < 16; ++r) {
            const size_t idx = (size_t)(blk * 16 + r) * DD + t;
            weak_s[r][t] = head_right[idx] - head_left[idx];
        }
        __syncthreads();

        float4 acc[4];
        #pragma unroll
        for (int r = 0; r < 4; ++r) acc[r] = make_float4(0.f, 0.f, 0.f, 0.f);
        for (int k = 0; k < DD; ++k) {
            const float4 w4 = *(const float4*)(bw + k * DD + 4 * lane);
            #pragma unroll
            for (int r = 0; r < 4; ++r) {
                const float x = weak_s[4 * w + r][k];
                acc[r].x += x * w4.x; acc[r].y += x * w4.y;
                acc[r].z += x * w4.z; acc[r].w += x * w4.w;
            }
        }
        #pragma unroll
        for (int r = 0; r < 4; ++r)
            *(float4*)(hW + (size_t)(blk * 16 + 4 * w + r) * DD + 4 * lane) = acc[r];
    }
}

// ---------------- attn (FROZEN round-8) + bf16 ctx emit ----------------
__global__ __launch_bounds__(256)
void k_attn(const float* __restrict__ rel_left,
            const float* __restrict__ tail_left,
            const float* __restrict__ rel_right,
            const float* __restrict__ tail_right,
            const unsigned char* __restrict__ mask_left,
            const unsigned char* __restrict__ mask_right,
            const float* __restrict__ hW,
            short* __restrict__ A_bf)
{
    const int b    = blockIdx.x >> 1;
    const int side = blockIdx.x & 1;
    const int t    = threadIdx.x;
    const int lane = t & 63;
    const int w    = t >> 6;

    const float* __restrict__ rel  = side ? rel_right  : rel_left;
    const float* __restrict__ tail = side ? tail_right : tail_left;
    const unsigned char* __restrict__ mask = side ? mask_right : mask_left;

    __shared__ float part_s[MM][65];
    __shared__ float red_s[MM][5];
    __shared__ float att_s[MM];
    __shared__ float cpart_s[4][DD];

    const float4 hw4 = *(const float4*)(hW + (size_t)b * DD + 4 * lane);
    const float* rp = rel  + (size_t)b * MM * DD + 4 * lane;
    const float* tp = tail + (size_t)b * MM * DD + 4 * lane;

    #pragma unroll
    for (int i = 0; i < 16; ++i) {
        const int m = w * 16 + i;
        const f4v r4 = __builtin_nontemporal_load((const f4v*)(rp + (size_t)m * DD));
        part_s[m][lane] = hw4.x * r4.x + hw4.y * r4.y + hw4.z * r4.z + hw4.w * r4.w;
    }
    __syncthreads();

    {
        const int m = t & 63;
        const int c = t >> 6;
        float s = 0.f;
        #pragma unroll
        for (int j = 0; j < 16; ++j) s += part_s[m][c * 16 + j];
        red_s[m][c] = s;
    }
    __syncthreads();

    if (w == 0) {
        const unsigned char v0 = mask_left[lane];
        const bool mask_u8 = (__ballot(((lane & 3) != 0) && (v0 != 0)) != 0ULL);

        float s = red_s[lane][0] + red_s[lane][1] + red_s[lane][2] + red_s[lane][3];
        const bool msk = mask_u8
            ? (mask[(size_t)b * MM + lane] != 0)
            : (((const int*)(const void*)mask)[(size_t)b * MM + lane] != 0);
        if (msk) s = NEG_BIG;
        float mx = s;
        #pragma unroll
        for (int off = 32; off >= 1; off >>= 1) mx = fmaxf(mx, __shfl_xor(mx, off, 64));
        const float e = __expf(s - mx);
        float sum = e;
        #pragma unroll
        for (int off = 32; off >= 1; off >>= 1) sum += __shfl_xor(sum, off, 64);
        att_s[lane] = e / sum;
    }
    __syncthreads();

    float4 acc = make_float4(0.f, 0.f, 0.f, 0.f);
    #pragma unroll 4
    for (int i = 0; i < 16; ++i) {
        const int m = w * 16 + i;
        const float a  = att_s[m];
        const f4v v = __builtin_nontemporal_load((const f4v*)(tp + (size_t)m * DD));
        acc.x += a * v.x; acc.y += a * v.y; acc.z += a * v.z; acc.w += a * v.w;
    }
    *(float4*)(&cpart_s[w][4 * lane]) = acc;
    __syncthreads();

    const float sum = cpart_s[0][t] + cpart_s[1][t] + cpart_s[2][t] + cpart_s[3][t];
    A_bf[(size_t)(side * NB + b) * 256 + t] = (short)f2bf(sum);
}

// ---------------- fuse: MFMA GEMM [32x256,K=512] + relu + residual + LN ----------------
// 256 blocks x 512 threads (8 waves). wave w: rows wr*16..+15 (wr=w>>2), cols wc*64..+63 (wc=w&3).
// K half 1 (k=0..255):   A = ctx bf16 from A_bf (nontemporal, read-once)
// K half 2 (k=256..511): A = head f32 converted in-register (head re-read later for residual
//                        hits L1/L2 — no materialized bf16 head copy needed)
// Shared k rule for A and B frags: k = ks*32 + (l>>4)*8 + j  [validated rounds 10-11]
// C/D: col = lane&15, row = (lane>>4)*4 + reg                [HW-verified m89]
__global__ __launch_bounds__(512)
void k_fuse(const short* __restrict__ A_bf,
            const short* __restrict__ Bp,
            const float* __restrict__ head_left,
            const float* __restrict__ head_right,
            const float* __restrict__ gamma,
            const float* __restrict__ beta,
            float* __restrict__ out)
{
    const int blk  = blockIdx.x;          // 256 blocks x 32 rows
    const int t    = threadIdx.x;
    const int lane = t & 63;
    const int w    = t >> 6;
    const int wr   = w >> 2;
    const int wc   = w & 3;
    const int rg0  = blk * 32;

    __shared__ float x_s[32][260];        // pad 260: acc-write groups 2-way only (free)

    const int  side = rg0 >> 12;          // block-uniform
    const float* __restrict__ head = side ? head_right : head_left;

    f32x4 acc[4] = {f32x4{0,0,0,0}, f32x4{0,0,0,0}, f32x4{0,0,0,0}, f32x4{0,0,0,0}};

    const int arow = rg0 + wr * 16 + (lane & 15);      // global A row for this lane
    const short* ap = A_bf + (size_t)arow * 256 + (lane >> 4) * 8;
    const float* hp = head + (size_t)(arow & (NB - 1)) * DD + (lane >> 4) * 8;
    const short* bp = Bp + (size_t)(wc * 64 + (lane & 15)) * 32 + (lane >> 4) * 8;

    // ---- K half 1: ctx ----
    #pragma unroll 4
    for (int ks = 0; ks < 8; ++ks) {
        const bf16x8 a = __builtin_nontemporal_load((const bf16x8*)(ap + ks * 32));
        #pragma unroll
        for (int ct = 0; ct < 4; ++ct) {
            const bf16x8 b = *(const bf16x8*)(bp + (size_t)ks * 8192 + ct * 512);
            acc[ct] = __builtin_amdgcn_mfma_f32_16x16x32_bf16(a, b, acc[ct], 0, 0, 0);
        }
    }
    // ---- K half 2: head, converted in-register ----
    #pragma unroll 4
    for (int ks = 8; ks < 16; ++ks) {
        const f4v h0 = *(const f4v*)(hp + (ks - 8) * 32);
        const f4v h1 = *(const f4v*)(hp + (ks - 8) * 32 + 4);
        bf16x8 a;
        a[0] = (short)f2bf(h0.x); a[1] = (short)f2bf(h0.y);
        a[2] = (short)f2bf(h0.z); a[3] = (short)f2bf(h0.w);
        a[4] = (short)f2bf(h1.x); a[5] = (short)f2bf(h1.y);
        a[6] = (short)f2bf(h1.z); a[7] = (short)f2bf(h1.w);
        #pragma unroll
        for (int ct = 0; ct < 4; ++ct) {
            const bf16x8 b = *(const bf16x8*)(bp + (size_t)ks * 8192 + ct * 512);
            acc[ct] = __builtin_amdgcn_mfma_f32_16x16x32_bf16(a, b, acc[ct], 0, 0, 0);
        }
    }

    #pragma unroll
    for (int ct = 0; ct < 4; ++ct)
        #pragma unroll
        for (int q = 0; q < 4; ++q)
            x_s[wr * 16 + (lane >> 4) * 4 + q][wc * 64 + ct * 16 + (lane & 15)] = acc[ct][q];
    __syncthreads();

    // LN: wave w owns rows 4w..4w+3; lane covers cols 4*lane..+3
    const float4 g4 = *(const float4*)(gamma + 4 * lane);
    const float4 b4 = *(const float4*)(beta  + 4 * lane);

    #pragma unroll
    for (int rr = 0; rr < 4; ++rr) {
        const int r  = 4 * w + rr;
        const int rg = rg0 + r;
        const int bb = rg & (NB - 1);
        const float4 v  = *(const float4*)(&x_s[r][4 * lane]);
        const float4 h4 = *(const float4*)(head + (size_t)bb * DD + 4 * lane);
        float4 y;
        y.x = fmaxf(v.x, 0.f) + h4.x;
        y.y = fmaxf(v.y, 0.f) + h4.y;
        y.z = fmaxf(v.z, 0.f) + h4.z;
        y.w = fmaxf(v.w, 0.f) + h4.w;

        float s1 = y.x + y.y + y.z + y.w;
        float s2 = y.x * y.x + y.y * y.y + y.z * y.z + y.w * y.w;
        #pragma unroll
        for (int off = 32; off >= 1; off >>= 1) {
            s1 += __shfl_xor(s1, off, 64);
            s2 += __shfl_xor(s2, off, 64);
        }
        const float mu   = s1 * (1.0f / DD);
        const float var  = s2 * (1.0f / DD) - mu * mu;
        const float rstd = rsqrtf(var + LN_EPS);

        f4v o;
        o.x = (y.x - mu) * rstd * g4.x + b4.x;
        o.y = (y.y - mu) * rstd * g4.y + b4.y;
        o.z = (y.z - mu) * rstd * g4.z + b4.z;
        o.w = (y.w - mu) * rstd * g4.w + b4.w;
        __builtin_nontemporal_store(o, (f4v*)(out + (size_t)rg * DD + 4 * lane));
    }
}

extern "C" void kernel_launch(void* const* d_in, const int* in_sizes, int n_in,
                              void* d_out, int out_size, void* d_ws, size_t ws_size,
                              hipStream_t stream) {
    const float* head_left  = (const float*)d_in[0];
    const float* rel_left   = (const float*)d_in[1];
    const float* tail_left  = (const float*)d_in[2];
    const float* head_right = (const float*)d_in[3];
    const float* rel_right  = (const float*)d_in[4];
    const float* tail_right = (const float*)d_in[5];
    const unsigned char* mask_left  = (const unsigned char*)d_in[6];
    const unsigned char* mask_right = (const unsigned char*)d_in[7];
    const float* bw    = (const float*)d_in[8];
    const float* wt    = (const float*)d_in[9];
    const float* wh    = (const float*)d_in[10];
    const float* gamma = (const float*)d_in[11];
    const float* beta  = (const float*)d_in[12];
    float* out = (float*)d_out;

    float* ws   = (float*)d_ws;
    float* hW   = ws + WS_HW;
    short* A_bf = (short*)(ws + NB * DD);
    short* Bp   = A_bf + (size_t)8192 * 256;

    k_prep <<<dim3(272),  dim3(256), 0, stream>>>(head_left, head_right, bw, wt, wh,
                                                  Bp, hW);
    k_attn <<<dim3(8192), dim3(256), 0, stream>>>(rel_left, tail_left, rel_right, tail_right,
                                                  mask_left, mask_right, hW, A_bf);
    k_fuse <<<dim3(256),  dim3(512), 0, stream>>>(A_bf, Bp, head_left, head_right,
                                                  gamma, beta, out);
}